// Round 7
// baseline (204.150 us; speedup 1.0000x reference)
//
#include <hip/hip_runtime.h>
#include <hip/hip_bf16.h>
#include <cstdint>

#define NN 8192
#define F 512
#define LOG2E 1.4426950408889634f

typedef __attribute__((ext_vector_type(8))) short bf16x8;
typedef __attribute__((ext_vector_type(4))) float f32x4;
typedef unsigned int uint32;
typedef unsigned long long u64;
typedef unsigned char uchar;

#define AS1 __attribute__((address_space(1)))
#define AS3 __attribute__((address_space(3)))
__device__ __forceinline__ void gload16(const void* g, void* l){
  __builtin_amdgcn_global_load_lds((const AS1 uint32*)g, (AS3 uint32*)l, 16, 0, 0);
}

__device__ __forceinline__ short f2bf(float x){
  __hip_bfloat16 h = __float2bfloat16(x);
  return *reinterpret_cast<short*>(&h);
}

// ---------- wa = W @ a1 / W @ a2 ----------
__global__ __launch_bounds__(256) void k_wa(const float* __restrict__ W, const float* __restrict__ attn,
                     float* __restrict__ wa){
  const int lane = threadIdx.x&63, wid = threadIdx.x>>6;
  const int id = blockIdx.x*4 + wid;
  const int b = id>>9, c = id&511;
  const float4* Wr = (const float4*)(W + (size_t)c*F);
  const float4* av = (const float4*)(attn + b*F);
  float s = 0.f;
  #pragma unroll
  for (int h=0;h<2;++h){
    const int k = lane + h*64;
    const float4 wv = Wr[k], a = av[k];
    s += wv.x*a.x + wv.y*a.y + wv.z*a.z + wv.w*a.w;
  }
  for (int off=32;off;off>>=1) s += __shfl_down(s,off);
  if (lane==0) wa[id] = s;
}

// ---------- W^T -> bf16 via LDS tile ----------
__global__ __launch_bounds__(256) void k_tw(const float* __restrict__ W, short* __restrict__ WbT){
  __shared__ short t[64][72];
  const int k0 = blockIdx.x*64, n0 = blockIdx.y*64;
  #pragma unroll
  for (int it=0;it<16;++it){
    const int idx = it*256 + threadIdx.x;
    const int r = idx>>6, c = idx&63;
    t[r][c] = f2bf(W[(size_t)(k0+r)*F + n0 + c]);
  }
  __syncthreads();
  #pragma unroll
  for (int it=0;it<2;++it){
    const int idx = it*256 + threadIdx.x;
    const int n = idx>>3, g = idx&7;
    short v[8];
    #pragma unroll
    for (int e=0;e<8;++e) v[e] = t[g*8+e][n];
    *(uint4*)(WbT + (size_t)(n0+n)*F + k0 + g*8) = *(const uint4*)v;
  }
}

// ---------- fused: X->bf16 + rowAB (exp2 of s1 terms) + packed bf16 (u,w) ----------
__global__ __launch_bounds__(256) void k_prep(const float* __restrict__ X, const float* __restrict__ wa,
    short* __restrict__ Xb, float2* __restrict__ rowAB, uint32* __restrict__ uwb){
  const int lane = threadIdx.x&63, wid = threadIdx.x>>6;
  const int row = blockIdx.x*4 + wid;
  const float4* X4 = (const float4*)(X + (size_t)row*F);
  const float4* A4 = (const float4*)wa;
  const float4* B4 = (const float4*)(wa + F);
  uint2* Xb4 = (uint2*)(Xb + (size_t)row*F);
  float a1 = 0.f, a2 = 0.f;
  #pragma unroll
  for (int h=0;h<2;++h){
    const int c = lane + h*64;
    const float4 x = X4[c];
    const float4 a = A4[c];
    const float4 b = B4[c];
    a1 += x.x*a.x + x.y*a.y + x.z*a.z + x.w*a.w;
    a2 += x.x*b.x + x.y*b.y + x.z*b.z + x.w*b.w;
    short o[4] = {f2bf(x.x),f2bf(x.y),f2bf(x.z),f2bf(x.w)};
    Xb4[c] = *(const uint2*)o;
  }
  for (int off=32;off;off>>=1){ a1 += __shfl_down(a1,off); a2 += __shfl_down(a2,off); }
  if (lane==0){
    const float s1 = a1*LOG2E, s2 = a2*LOG2E;
    rowAB[row] = make_float2(exp2f(s1), exp2f(0.2f*s1));
    const float u = exp2f(s2), w = exp2f(0.2f*s2);
    uwb[row] = (uint32)(unsigned short)f2bf(u) | ((uint32)(unsigned short)f2bf(w)<<16);
  }
}

// ---------- GEMM1: h = Xb @ WbT^T, writes HT[feature][node] bf16 ----------
__global__ __launch_bounds__(256,2) void k_gemm1(const short* __restrict__ Xb,
    const short* __restrict__ WbT, short* __restrict__ HT){
  __shared__ char smem[33280];
  short* At = (short*)smem;
  short* Bt = (short*)(smem + 16384);
  const int tid=threadIdx.x, lane=tid&63, wid=tid>>6;
  const int m0 = blockIdx.x*128, n0 = blockIdx.y*128;
  f32x4 acc[2][8];
  #pragma unroll
  for (int a=0;a<2;++a)
    #pragma unroll
    for (int b=0;b<8;++b) acc[a][b] = (f32x4){0.f,0.f,0.f,0.f};

  for (int t=0;t<8;++t){
    const int k0 = t*64;
    __syncthreads();
    #pragma unroll
    for (int rnd=0;rnd<4;++rnd){
      const int s = rnd*256 + tid;
      const int n = s>>3, kc = s&7;
      uint4 va = *(const uint4*)(Xb  + (size_t)(m0+n)*F + k0 + kc*8);
      uint4 vb = *(const uint4*)(WbT + (size_t)(n0+n)*F + k0 + kc*8);
      const int off = n*128 + ((kc^(n&7))*16);
      *(uint4*)((char*)At + off) = va;
      *(uint4*)((char*)Bt + off) = vb;
    }
    __syncthreads();
    #pragma unroll
    for (int ks=0;ks<2;++ks){
      const int kc = ks*4 + (lane>>4);
      int r0 = wid*32 + (lane&15);
      int r1 = r0 + 16;
      bf16x8 af0 = *(const bf16x8*)((char*)At + r0*128 + ((kc^(r0&7))*16));
      bf16x8 af1 = *(const bf16x8*)((char*)At + r1*128 + ((kc^(r1&7))*16));
      #pragma unroll
      for (int nf=0;nf<8;++nf){
        const int c = nf*16 + (lane&15);
        bf16x8 bf = *(const bf16x8*)((char*)Bt + c*128 + ((kc^(c&7))*16));
        acc[0][nf] = __builtin_amdgcn_mfma_f32_16x16x32_bf16(af0, bf, acc[0][nf],0,0,0);
        acc[1][nf] = __builtin_amdgcn_mfma_f32_16x16x32_bf16(af1, bf, acc[1][nf],0,0,0);
      }
    }
  }
  __syncthreads();
  short* ct = (short*)smem;                 // [128][130] bf16
  #pragma unroll
  for (int mf=0;mf<2;++mf)
    #pragma unroll
    for (int nf=0;nf<8;++nf)
      #pragma unroll
      for (int q=0;q<4;++q){
        int r = wid*32 + mf*16 + (lane>>4)*4 + q;
        int c = nf*16 + (lane&15);
        ct[r*130+c] = f2bf(acc[mf][nf][q]);
      }
  __syncthreads();
  {
    const int c = tid>>1, ih0 = (tid&1)*64;
    #pragma unroll
    for (int i8=0;i8<8;++i8){
      short v[8];
      #pragma unroll
      for (int e=0;e<8;++e) v[e] = ct[(ih0+i8*8+e)*130 + c];
      *(uint4*)(HT + (size_t)(n0+c)*NN + m0 + ih0 + i8*8) = *(const uint4*)v;
    }
  }
}

// ---------- PV fused: adjacency stream + on-the-fly weights + MFMA, counted-vmcnt pipeline ----------
// BM=64, BN=512 (adj read once), BK=32, double-buffered B(2x32K)+A(2x4K), split-K=4.
__global__ __launch_bounds__(256,2) void k_pv(const int* __restrict__ adj,
    const short* __restrict__ HT, const uint32* __restrict__ uwb,
    const float2* __restrict__ rowAB, float* __restrict__ Zp,
    float* __restrict__ P0, float* __restrict__ P1,
    float* __restrict__ P2, float* __restrict__ P3, int ksteps){
  __shared__ short Bt2[2][512*32];   // 2 x 32 KB, swizzled [feature][chunk]
  __shared__ short At2[2][64*32];    // 2 x 4 KB, swizzled weights
  const int tid=threadIdx.x, lane=tid&63, wid=tid>>6;
  const int m0 = blockIdx.x*64;
  const int kz = blockIdx.y;
  const int kz0 = kz*(ksteps*32);
  float* const outs[4] = {P0,P1,P2,P3};
  float* outP = outs[kz];

  // B staging geometry: wave stages features [wid*128, +128), 8 gload16/step.
  // lane l -> feature fb = wid*128 + (l>>2), chunk cc = l&3 holding kc = cc^(fb&3).
  const int fb = wid*128 + (lane>>2);
  const int ccs = (lane&3) ^ ((lane>>2)&3);
  const short* gB0 = HT + (size_t)fb*NN + kz0 + ccs*8;     // + i*16*NN + t*32
  const uint32 ldsOff = (uint32)(wid*8192 + lane*16);      // + i*1024, within Bt2[buf]

  // A-gen geometry: r = tid>>2 (row), q = tid&3 (8-col group within 32-col step)
  const int r = tid>>2, q = tid&3;
  const float2 E = rowAB[m0 + r];
  const float A0 = E.x, B0 = E.y;
  const int*    adjp = adj + (size_t)(m0+r)*NN + kz0 + q*8;
  const uint32* uwp  = uwb + kz0 + q*8;
  const int aoff = r*64 + ((q ^ (r&3))<<4);

  f32x4 acc[4][8];
  #pragma unroll
  for (int i=0;i<4;++i)
    #pragma unroll
    for (int j=0;j<8;++j) acc[i][j] = (f32x4){0.f,0.f,0.f,0.f};
  float zacc = 0.f;

  int4  ra0, ra1;     // adjacency regs (8 ints)
  uint4 ru0, ru1;     // packed (u,w) regs (8 cols)

#define PV_LOADREGS(tt) { \
    ra0 = *(const int4*)(adjp + (size_t)(tt)*32); \
    ra1 = *(const int4*)(adjp + (size_t)(tt)*32 + 4); \
    ru0 = *(const uint4*)(uwp + (size_t)(tt)*32); \
    ru1 = *(const uint4*)(uwp + (size_t)(tt)*32 + 4); }

#define PV_STAGE_B(buf, tt) { \
    const short* gs = gB0 + (size_t)(tt)*32; \
    char* ld = (char*)(Bt2[buf]) + ldsOff; \
    _Pragma("unroll") \
    for (int i=0;i<8;++i) gload16(gs + (size_t)i*16*NN, ld + i*1024); }

#define PV_AGEN(abuf) { \
    const uint32 pk[8] = {ru0.x,ru0.y,ru0.z,ru0.w, ru1.x,ru1.y,ru1.z,ru1.w}; \
    const int    aa[8] = {ra0.x,ra0.y,ra0.z,ra0.w, ra1.x,ra1.y,ra1.z,ra1.w}; \
    short av[8]; \
    _Pragma("unroll") \
    for (int e=0;e<8;++e){ \
      const float u = __uint_as_float(pk[e]<<16); \
      const float w = __uint_as_float(pk[e]&0xffff0000u); \
      float v = fmaxf(A0*u, B0*w); \
      v = (aa[e] > 0) ? v : 0.f; \
      zacc += v; \
      av[e] = f2bf(v); } \
    *(uint4*)((char*)(At2[abuf]) + aoff) = *(const uint4*)av; }

#define PV_MFMA(buf) { \
    const int kc = lane>>4; \
    bf16x8 af[4]; \
    _Pragma("unroll") \
    for (int mf=0;mf<4;++mf){ \
      const int rr = mf*16 + (lane&15); \
      af[mf] = *(const bf16x8*)((char*)(At2[buf]) + rr*64 + ((kc^(rr&3))<<4)); } \
    _Pragma("unroll") \
    for (int nf=0;nf<8;++nf){ \
      const int c = wid*128 + nf*16 + (lane&15); \
      const bf16x8 bv = *(const bf16x8*)((char*)(Bt2[buf]) + c*64 + ((kc^(c&3))<<4)); \
      _Pragma("unroll") \
      for (int mf=0;mf<4;++mf) \
        acc[mf][nf] = __builtin_amdgcn_mfma_f32_16x16x32_bf16(af[mf], bv, acc[mf][nf],0,0,0); } }

  // ---- prologue: establish invariant {B(0).8, regs(1).4, B(1).8} outstanding, A(0) written
  PV_LOADREGS(0);            // regs(0).4
  PV_STAGE_B(0, 0);          // B(0).8
  PV_AGEN(0);                // consumes regs(0)  [auto vmcnt(8)]
  PV_LOADREGS(1);            // regs(1).4
  PV_STAGE_B(1, 1);          // B(1).8

  // ---- main loop: t = 0 .. ksteps-3
  for (int t=0; t<ksteps-2; ++t){
    asm volatile("s_waitcnt vmcnt(12) lgkmcnt(0)" ::: "memory");  // B(t) done, A writes flushed
    __builtin_amdgcn_s_barrier();
    __builtin_amdgcn_sched_barrier(0);
    PV_MFMA(t&1);
    PV_AGEN((t+1)&1);        // consumes regs(t+1) [auto vmcnt(8): B(t+1) stays in flight]
    __builtin_amdgcn_s_barrier();           // B[t&1] reads done before restage
    __builtin_amdgcn_sched_barrier(0);
    PV_LOADREGS(t+2);        // regs(t+2).4
    PV_STAGE_B(t&1, t+2);    // B(t+2).8
  }
  // ---- tail t = ksteps-2 (no new issues)
  {
    const int t = ksteps-2;
    asm volatile("s_waitcnt vmcnt(12) lgkmcnt(0)" ::: "memory");
    __builtin_amdgcn_s_barrier();
    __builtin_amdgcn_sched_barrier(0);
    PV_MFMA(t&1);
    PV_AGEN((t+1)&1);
    __builtin_amdgcn_s_barrier();
    __builtin_amdgcn_sched_barrier(0);
  }
  // ---- tail t = ksteps-1
  {
    const int t = ksteps-1;
    asm volatile("s_waitcnt vmcnt(0) lgkmcnt(0)" ::: "memory");
    __builtin_amdgcn_s_barrier();
    __builtin_amdgcn_sched_barrier(0);
    PV_MFMA(t&1);
  }

  // per-slice Z: 4 threads per row
  zacc += __shfl_xor(zacc, 1);
  zacc += __shfl_xor(zacc, 2);
  if (q == 0) Zp[(size_t)kz*NN + m0 + r] = zacc;
  // raw f32 partial store
  #pragma unroll
  for (int mf=0;mf<4;++mf)
    #pragma unroll
    for (int nf=0;nf<8;++nf){
      const int col = wid*128 + nf*16 + (lane&15);
      #pragma unroll
      for (int qq=0;qq<4;++qq){
        const int row = m0 + mf*16 + (lane>>4)*4 + qq;
        outP[(size_t)row*F + col] = acc[mf][nf][qq];
      }
    }
#undef PV_LOADREGS
#undef PV_STAGE_B
#undef PV_AGEN
#undef PV_MFMA
}

// ---------- reduce: out = elu( (P0+P1+P2+P3) / Z ) ----------
__global__ __launch_bounds__(256) void k_red(const float* __restrict__ P1,
    const float* __restrict__ P2, const float* __restrict__ P3,
    const float* __restrict__ Zp, float* __restrict__ out, int ks){
  const size_t i = ((size_t)blockIdx.x*256 + threadIdx.x)*4;
  const int row = (int)(i >> 9);
  float4 a = *(float4*)(out+i);
  float Z = Zp[row];
  if (ks > 1){
    Z += Zp[NN+row] + Zp[2*NN+row] + Zp[3*NN+row];
    const float4 b1 = *(const float4*)(P1+i);
    const float4 b2 = *(const float4*)(P2+i);
    const float4 b3 = *(const float4*)(P3+i);
    a.x += b1.x+b2.x+b3.x; a.y += b1.y+b2.y+b3.y;
    a.z += b1.z+b2.z+b3.z; a.w += b1.w+b2.w+b3.w;
  }
  const float s = 1.f/Z;
  a.x*=s; a.y*=s; a.z*=s; a.w*=s;
  a.x = (a.x>0.f)?a.x:expm1f(a.x);
  a.y = (a.y>0.f)?a.y:expm1f(a.y);
  a.z = (a.z>0.f)?a.z:expm1f(a.z);
  a.w = (a.w>0.f)?a.w:expm1f(a.w);
  *(float4*)(out+i) = a;
}

extern "C" void kernel_launch(void* const* d_in, const int* in_sizes, int n_in,
                              void* d_out, int out_size, void* d_ws, size_t ws_size,
                              hipStream_t stream) {
  (void)in_sizes; (void)n_in; (void)out_size;
  const int*   adj  = (const int*)d_in[0];
  const float* X    = (const float*)d_in[1];
  const float* W    = (const float*)d_in[2];
  const float* attn = (const float*)d_in[3];
  float* out = (float*)d_out;
  char* ws = (char*)d_ws;
  short*  HT   = (short*)(ws);                 // 8 MB
  short*  Xb   = (short*)(ws + 8388608);       // 8 MB
  short*  WbT  = (short*)(ws + 16777216);      // 0.5 MB
  uint32* uwb  = (uint32*)(ws + 17301504);     // 32 KB
  float2* rowAB= (float2*)(ws + 17334272);     // 64 KB
  float*  wa   = (float*)(ws + 17399808);      // 4 KB
  float*  Zp   = (float*)(ws + 17403904);      // 128 KB
  float*  P1   = (float*)(ws + 17534976);      // 16.78 MB
  float*  P2   = (float*)(ws + 34312192);      // 16.78 MB
  float*  P3   = (float*)(ws + 51089408);      // 16.78 MB (end ~68 MB)
  const int KS = (ws_size >= 67866624ull) ? 4 : 1;
  const int ksteps = 256/KS;                   // BK=32 steps per slice

  k_wa   <<<dim3(256),    dim3(256), 0, stream>>>(W, attn, wa);
  k_tw   <<<dim3(8,8),    dim3(256), 0, stream>>>(W, WbT);
  k_prep <<<dim3(2048),   dim3(256), 0, stream>>>(X, wa, Xb, rowAB, uwb);
  k_gemm1<<<dim3(64,4),   dim3(256), 0, stream>>>(Xb, WbT, HT);
  k_pv   <<<dim3(128,KS), dim3(256), 0, stream>>>(adj, HT, uwb, rowAB, Zp, out, P1, P2, P3, ksteps);
  k_red  <<<dim3(4096),   dim3(256), 0, stream>>>(P1, P2, P3, Zp, out, KS);
}

// Round 8
// 180.311 us; speedup vs baseline: 1.1322x; 1.1322x over previous
//
#include <hip/hip_runtime.h>
#include <hip/hip_bf16.h>
#include <cstdint>

#define NN 8192
#define F 512
#define LOG2E 1.4426950408889634f

typedef __attribute__((ext_vector_type(8))) short bf16x8;
typedef __attribute__((ext_vector_type(4))) float f32x4;
typedef unsigned int uint32;
typedef unsigned long long u64;
typedef unsigned char uchar;

__device__ __forceinline__ short f2bf(float x){
  __hip_bfloat16 h = __float2bfloat16(x);
  return *reinterpret_cast<short*>(&h);
}

// ---------- wa = W @ a1 / W @ a2 ----------
__global__ __launch_bounds__(256) void k_wa(const float* __restrict__ W, const float* __restrict__ attn,
                     float* __restrict__ wa){
  const int lane = threadIdx.x&63, wid = threadIdx.x>>6;
  const int id = blockIdx.x*4 + wid;
  const int b = id>>9, c = id&511;
  const float4* Wr = (const float4*)(W + (size_t)c*F);
  const float4* av = (const float4*)(attn + b*F);
  float s = 0.f;
  #pragma unroll
  for (int h=0;h<2;++h){
    const int k = lane + h*64;
    const float4 wv = Wr[k], a = av[k];
    s += wv.x*a.x + wv.y*a.y + wv.z*a.z + wv.w*a.w;
  }
  for (int off=32;off;off>>=1) s += __shfl_down(s,off);
  if (lane==0) wa[id] = s;
}

// ---------- W^T -> bf16 via LDS tile ----------
__global__ __launch_bounds__(256) void k_tw(const float* __restrict__ W, short* __restrict__ WbT){
  __shared__ short t[64][72];
  const int k0 = blockIdx.x*64, n0 = blockIdx.y*64;
  #pragma unroll
  for (int it=0;it<16;++it){
    const int idx = it*256 + threadIdx.x;
    const int r = idx>>6, c = idx&63;
    t[r][c] = f2bf(W[(size_t)(k0+r)*F + n0 + c]);
  }
  __syncthreads();
  #pragma unroll
  for (int it=0;it<2;++it){
    const int idx = it*256 + threadIdx.x;
    const int n = idx>>3, g = idx&7;
    short v[8];
    #pragma unroll
    for (int e=0;e<8;++e) v[e] = t[g*8+e][n];
    *(uint4*)(WbT + (size_t)(n0+n)*F + k0 + g*8) = *(const uint4*)v;
  }
}

// ---------- fused: X->bf16 + rowAB + packed bf16 (u,w) ----------
__global__ __launch_bounds__(256) void k_prep(const float* __restrict__ X, const float* __restrict__ wa,
    short* __restrict__ Xb, float2* __restrict__ rowAB, uint32* __restrict__ uwb){
  const int lane = threadIdx.x&63, wid = threadIdx.x>>6;
  const int row = blockIdx.x*4 + wid;
  const float4* X4 = (const float4*)(X + (size_t)row*F);
  const float4* A4 = (const float4*)wa;
  const float4* B4 = (const float4*)(wa + F);
  uint2* Xb4 = (uint2*)(Xb + (size_t)row*F);
  float a1 = 0.f, a2 = 0.f;
  #pragma unroll
  for (int h=0;h<2;++h){
    const int c = lane + h*64;
    const float4 x = X4[c];
    const float4 a = A4[c];
    const float4 b = B4[c];
    a1 += x.x*a.x + x.y*a.y + x.z*a.z + x.w*a.w;
    a2 += x.x*b.x + x.y*b.y + x.z*b.z + x.w*b.w;
    short o[4] = {f2bf(x.x),f2bf(x.y),f2bf(x.z),f2bf(x.w)};
    Xb4[c] = *(const uint2*)o;
  }
  for (int off=32;off;off>>=1){ a1 += __shfl_down(a1,off); a2 += __shfl_down(a2,off); }
  if (lane==0){
    const float s1 = a1*LOG2E, s2 = a2*LOG2E;
    rowAB[row] = make_float2(exp2f(s1), exp2f(0.2f*s1));
    const float u = exp2f(s2), w = exp2f(0.2f*s2);
    uwb[row] = (uint32)(unsigned short)f2bf(u) | ((uint32)(unsigned short)f2bf(w)<<16);
  }
}

// ---------- GEMM1: h = Xb @ WbT^T, writes HT[feature][node] bf16 ----------
__global__ __launch_bounds__(256,2) void k_gemm1(const short* __restrict__ Xb,
    const short* __restrict__ WbT, short* __restrict__ HT){
  __shared__ char smem[33280];
  short* At = (short*)smem;
  short* Bt = (short*)(smem + 16384);
  const int tid=threadIdx.x, lane=tid&63, wid=tid>>6;
  const int m0 = blockIdx.x*128, n0 = blockIdx.y*128;
  f32x4 acc[2][8];
  #pragma unroll
  for (int a=0;a<2;++a)
    #pragma unroll
    for (int b=0;b<8;++b) acc[a][b] = (f32x4){0.f,0.f,0.f,0.f};

  for (int t=0;t<8;++t){
    const int k0 = t*64;
    __syncthreads();
    #pragma unroll
    for (int rnd=0;rnd<4;++rnd){
      const int s = rnd*256 + tid;
      const int n = s>>3, kc = s&7;
      uint4 va = *(const uint4*)(Xb  + (size_t)(m0+n)*F + k0 + kc*8);
      uint4 vb = *(const uint4*)(WbT + (size_t)(n0+n)*F + k0 + kc*8);
      const int off = n*128 + ((kc^(n&7))*16);
      *(uint4*)((char*)At + off) = va;
      *(uint4*)((char*)Bt + off) = vb;
    }
    __syncthreads();
    #pragma unroll
    for (int ks=0;ks<2;++ks){
      const int kc = ks*4 + (lane>>4);
      int r0 = wid*32 + (lane&15);
      int r1 = r0 + 16;
      bf16x8 af0 = *(const bf16x8*)((char*)At + r0*128 + ((kc^(r0&7))*16));
      bf16x8 af1 = *(const bf16x8*)((char*)At + r1*128 + ((kc^(r1&7))*16));
      #pragma unroll
      for (int nf=0;nf<8;++nf){
        const int c = nf*16 + (lane&15);
        bf16x8 bf = *(const bf16x8*)((char*)Bt + c*128 + ((kc^(c&7))*16));
        acc[0][nf] = __builtin_amdgcn_mfma_f32_16x16x32_bf16(af0, bf, acc[0][nf],0,0,0);
        acc[1][nf] = __builtin_amdgcn_mfma_f32_16x16x32_bf16(af1, bf, acc[1][nf],0,0,0);
      }
    }
  }
  __syncthreads();
  short* ct = (short*)smem;                 // [128][130] bf16
  #pragma unroll
  for (int mf=0;mf<2;++mf)
    #pragma unroll
    for (int nf=0;nf<8;++nf)
      #pragma unroll
      for (int q=0;q<4;++q){
        int r = wid*32 + mf*16 + (lane>>4)*4 + q;
        int c = nf*16 + (lane&15);
        ct[r*130+c] = f2bf(acc[mf][nf][q]);
      }
  __syncthreads();
  {
    const int c = tid>>1, ih0 = (tid&1)*64;
    #pragma unroll
    for (int i8=0;i8<8;++i8){
      short v[8];
      #pragma unroll
      for (int e=0;e<8;++e) v[e] = ct[(ih0+i8*8+e)*130 + c];
      *(uint4*)(HT + (size_t)(n0+c)*NN + m0 + ih0 + i8*8) = *(const uint4*)v;
    }
  }
}

// ---------- PV fused v3: reg-staged B (T14 issue-early/write-late), dbuf LDS ----------
// BM=64, BN=512, BK=32, 4 waves of 64x128, split-K=4. 80KB LDS -> 2 blocks/CU.
__global__ __launch_bounds__(256,2) void k_pv(const int* __restrict__ adj,
    const short* __restrict__ HT, const uint32* __restrict__ uwb,
    const float2* __restrict__ rowAB, float* __restrict__ Zp,
    float* __restrict__ P0, float* __restrict__ P1,
    float* __restrict__ P2, float* __restrict__ P3, int ksteps){
  __shared__ short Bt2[2][512*32];   // 2 x 32 KB : rows = feature, 64B/row, slot^=(f>>1)&3
  __shared__ short At2[2][64*32];    // 2 x 4 KB  : rows = out-row, same swizzle
  __shared__ uint32 uwl[2048];       // 8 KB packed bf16 (u,w) for this k-slice
  const int tid=threadIdx.x, lane=tid&63, wid=tid>>6;
  const int m0 = blockIdx.x*64;
  const int kz = blockIdx.y;
  const int kz0 = kz*(ksteps*32);
  float* const outs[4] = {P0,P1,P2,P3};
  float* outP = outs[kz];

  // ---- stage uw slice (2048 u32) ----
  {
    const uint4* src = (const uint4*)(uwb + kz0);
    uint4 v0 = src[tid], v1 = src[256+tid];
    ((uint4*)uwl)[tid] = v0; ((uint4*)uwl)[256+tid] = v1;
  }

  // ---- B staging geometry: thread covers features f = i*64 + (tid>>2), slot s=tid&3
  const int kcs = (tid&3) ^ ((tid>>3)&3);                 // source k-chunk (slot^x(f))
  const short* gB = HT + (size_t)(tid>>2)*NN + kz0 + kcs*8;  // + i*64*NN + t*32

  // ---- AGEN geometry: row ar=tid>>2, col-group aq=tid&3 (8 cols each)
  const int ar = tid>>2, aq = tid&3;
  const float2 E = rowAB[m0 + ar];
  const float A0 = E.x, B0c = E.y;
  const int* adjp = adj + (size_t)(m0+ar)*NN + kz0 + aq*8;
  const int aoff = ar*64 + ((aq ^ ((ar>>1)&3))<<4);

  // ---- MFMA geometry: lane-constant swizzled byte offset
  const int bofs = (((lane>>4) ^ ((lane>>1)&3))<<4);
  const int l15_64 = (lane&15)*64;

  f32x4 acc[4][8];
  #pragma unroll
  for (int i=0;i<4;++i)
    #pragma unroll
    for (int j=0;j<8;++j) acc[i][j] = (f32x4){0.f,0.f,0.f,0.f};
  float zacc = 0.f;

  uint4 b0,b1,b2,b3,b4,b5,b6,b7;   // B regs (one step)
  int4  aA0,aA1, aB0,aB1;          // adjacency ping-pong sets

#define PV_BLOAD(tt) { \
    const short* g = gB + (size_t)(tt)*32; \
    b0 = *(const uint4*)(g);               b1 = *(const uint4*)(g + (size_t)1*64*NN); \
    b2 = *(const uint4*)(g + (size_t)2*64*NN); b3 = *(const uint4*)(g + (size_t)3*64*NN); \
    b4 = *(const uint4*)(g + (size_t)4*64*NN); b5 = *(const uint4*)(g + (size_t)5*64*NN); \
    b6 = *(const uint4*)(g + (size_t)6*64*NN); b7 = *(const uint4*)(g + (size_t)7*64*NN); }

#define PV_BWRITE(buf) { \
    uint4* d = (uint4*)(Bt2[buf]); \
    d[      tid] = b0; d[ 256+tid] = b1; d[ 512+tid] = b2; d[ 768+tid] = b3; \
    d[1024+tid] = b4; d[1280+tid] = b5; d[1536+tid] = b6; d[1792+tid] = b7; }

#define PV_ALOAD(r0v,r1v,tt) { \
    r0v = *(const int4*)(adjp + (size_t)(tt)*32); \
    r1v = *(const int4*)(adjp + (size_t)(tt)*32 + 4); }

#define PV_AGEN(abuf, r0v, r1v, tt) { \
    const uint32* uwt = &uwl[(tt)*32 + aq*8]; \
    const uint4 u0 = *(const uint4*)uwt; \
    const uint4 u1 = *(const uint4*)(uwt+4); \
    const uint32 pk[8] = {u0.x,u0.y,u0.z,u0.w,u1.x,u1.y,u1.z,u1.w}; \
    const int    aa[8] = {r0v.x,r0v.y,r0v.z,r0v.w,r1v.x,r1v.y,r1v.z,r1v.w}; \
    short av[8]; \
    _Pragma("unroll") \
    for (int e=0;e<8;++e){ \
      const float u = __uint_as_float(pk[e]<<16); \
      const float w = __uint_as_float(pk[e]&0xffff0000u); \
      float v = fmaxf(A0*u, B0c*w); \
      v = (aa[e] > 0) ? v : 0.f; \
      zacc += v; \
      av[e] = f2bf(v); } \
    *(uint4*)((char*)(At2[abuf]) + aoff) = *(const uint4*)av; }

#define PV_MFMA(buf) { \
    bf16x8 af[4]; \
    _Pragma("unroll") \
    for (int mf=0;mf<4;++mf) \
      af[mf] = *(const bf16x8*)((char*)(At2[buf]) + mf*1024 + l15_64 + bofs); \
    _Pragma("unroll") \
    for (int nf=0;nf<8;++nf){ \
      const bf16x8 bv = *(const bf16x8*)((char*)(Bt2[buf]) + wid*8192 + nf*1024 + l15_64 + bofs); \
      _Pragma("unroll") \
      for (int mf=0;mf<4;++mf) \
        acc[mf][nf] = __builtin_amdgcn_mfma_f32_16x16x32_bf16(af[mf], bv, acc[mf][nf],0,0,0); } }

  // ---- prologue ----
  PV_ALOAD(aA0,aA1, 0);
  PV_BLOAD(0);
  __syncthreads();               // uwl visible
  PV_AGEN(0, aA0,aA1, 0);
  PV_BWRITE(0);
  PV_ALOAD(aB0,aB1, 1);
  __syncthreads();               // A[0], B[0] visible

  // ---- main loop, unrolled x2 for static reg-set selection ----
  for (int t=0; t<ksteps; t+=2){
    // even iter t: consume adj set B (t+1), refill set A (t+2)
    {
      if (t+1 < ksteps) PV_BLOAD(t+1);
      if (t+2 < ksteps) PV_ALOAD(aA0,aA1, t+2);
      PV_MFMA(0);
      if (t+1 < ksteps){ PV_AGEN(1, aB0,aB1, t+1); PV_BWRITE(1); }
      __syncthreads();
    }
    // odd iter t+1: consume adj set A (t+2), refill set B (t+3)
    if (t+1 < ksteps){
      if (t+2 < ksteps) PV_BLOAD(t+2);
      if (t+3 < ksteps) PV_ALOAD(aB0,aB1, t+3);
      PV_MFMA(1);
      if (t+2 < ksteps){ PV_AGEN(0, aA0,aA1, t+2); PV_BWRITE(0); }
      __syncthreads();
    }
  }

  // per-slice Z: 4 threads per row
  zacc += __shfl_xor(zacc, 1);
  zacc += __shfl_xor(zacc, 2);
  if (aq == 0) Zp[(size_t)kz*NN + m0 + ar] = zacc;
  // raw f32 partial store
  #pragma unroll
  for (int mf=0;mf<4;++mf)
    #pragma unroll
    for (int nf=0;nf<8;++nf){
      const int col = wid*128 + nf*16 + (lane&15);
      #pragma unroll
      for (int qq=0;qq<4;++qq){
        const int row = m0 + mf*16 + (lane>>4)*4 + qq;
        outP[(size_t)row*F + col] = acc[mf][nf][qq];
      }
    }
#undef PV_BLOAD
#undef PV_BWRITE
#undef PV_ALOAD
#undef PV_AGEN
#undef PV_MFMA
}

// ---------- reduce: out = elu( (P0+P1+P2+P3) / Z ) ----------
__global__ __launch_bounds__(256) void k_red(const float* __restrict__ P1,
    const float* __restrict__ P2, const float* __restrict__ P3,
    const float* __restrict__ Zp, float* __restrict__ out, int ks){
  const size_t i = ((size_t)blockIdx.x*256 + threadIdx.x)*4;
  const int row = (int)(i >> 9);
  float4 a = *(float4*)(out+i);
  float Z = Zp[row];
  if (ks > 1){
    Z += Zp[NN+row] + Zp[2*NN+row] + Zp[3*NN+row];
    const float4 b1 = *(const float4*)(P1+i);
    const float4 b2 = *(const float4*)(P2+i);
    const float4 b3 = *(const float4*)(P3+i);
    a.x += b1.x+b2.x+b3.x; a.y += b1.y+b2.y+b3.y;
    a.z += b1.z+b2.z+b3.z; a.w += b1.w+b2.w+b3.w;
  }
  const float s = 1.f/Z;
  a.x*=s; a.y*=s; a.z*=s; a.w*=s;
  a.x = (a.x>0.f)?a.x:expm1f(a.x);
  a.y = (a.y>0.f)?a.y:expm1f(a.y);
  a.z = (a.z>0.f)?a.z:expm1f(a.z);
  a.w = (a.w>0.f)?a.w:expm1f(a.w);
  *(float4*)(out+i) = a;
}

extern "C" void kernel_launch(void* const* d_in, const int* in_sizes, int n_in,
                              void* d_out, int out_size, void* d_ws, size_t ws_size,
                              hipStream_t stream) {
  (void)in_sizes; (void)n_in; (void)out_size;
  const int*   adj  = (const int*)d_in[0];
  const float* X    = (const float*)d_in[1];
  const float* W    = (const float*)d_in[2];
  const float* attn = (const float*)d_in[3];
  float* out = (float*)d_out;
  char* ws = (char*)d_ws;
  short*  HT   = (short*)(ws);                 // 8 MB
  short*  Xb   = (short*)(ws + 8388608);       // 8 MB
  short*  WbT  = (short*)(ws + 16777216);      // 0.5 MB
  uint32* uwb  = (uint32*)(ws + 17301504);     // 32 KB
  float2* rowAB= (float2*)(ws + 17334272);     // 64 KB
  float*  wa   = (float*)(ws + 17399808);      // 4 KB
  float*  Zp   = (float*)(ws + 17403904);      // 128 KB
  float*  P1   = (float*)(ws + 17534976);      // 16.78 MB
  float*  P2   = (float*)(ws + 34312192);      // 16.78 MB
  float*  P3   = (float*)(ws + 51089408);      // 16.78 MB (end ~68 MB)
  const int KS = (ws_size >= 67866624ull) ? 4 : 1;
  const int ksteps = 256/KS;                   // BK=32 steps per slice

  k_wa   <<<dim3(256),    dim3(256), 0, stream>>>(W, attn, wa);
  k_tw   <<<dim3(8,8),    dim3(256), 0, stream>>>(W, WbT);
  k_prep <<<dim3(2048),   dim3(256), 0, stream>>>(X, wa, Xb, rowAB, uwb);
  k_gemm1<<<dim3(64,4),   dim3(256), 0, stream>>>(Xb, WbT, HT);
  k_pv   <<<dim3(128,KS), dim3(256), 0, stream>>>(adj, HT, uwb, rowAB, Zp, out, P1, P2, P3, ksteps);
  k_red  <<<dim3(4096),   dim3(256), 0, stream>>>(P1, P2, P3, Zp, out, KS);
}